// Round 3
// baseline (226.421 us; speedup 1.0000x reference)
//
#include <hip/hip_runtime.h>
#include <hip/hip_bf16.h>
#include <cstdint>
#include <cstddef>

// Problem constants
#define BS_TOT  12288   // 3 * 4096 rows
#define DIM     256     // embedding dim
#define BATCH_  4096
#define NTILE   96      // BS_TOT / 128
#define NPAIR   4656    // NTILE*(NTILE+1)/2 — triangular tile pairs (incl diag)
#define NBLOCKS 512     // persistent, 2 blocks/CU; ~9 contiguous pairs each

typedef float f32x16 __attribute__((ext_vector_type(16)));
typedef int   i32x8  __attribute__((ext_vector_type(8)));

// ---------------------------------------------------------------------------
// Kernel 1: row-normalize -> fp8 e4m3 rows scaled by sqrt(10*log2(e)):
// acc = 10*log2(e)*cos, so epilogue exp(10 cos) = exp2(acc) = bare v_exp_f32.
// Also fp32 inv-norms (exact numerator path) + zero den + zero out.
// ---------------------------------------------------------------------------
__global__ __launch_bounds__(256) void normalize_kernel(const float* __restrict__ x,
                                                        uint8_t* __restrict__ xn,
                                                        float* __restrict__ invn,
                                                        float* __restrict__ den,
                                                        float* __restrict__ out,
                                                        int osz) {
  if (blockIdx.x == 0 && (int)threadIdx.x < osz) out[threadIdx.x] = 0.0f;
  const int wave = threadIdx.x >> 6;
  const int lane = threadIdx.x & 63;
  const int row  = blockIdx.x * 4 + wave;
  const float4 v = ((const float4*)(x + (size_t)row * DIM))[lane];
  float ss = v.x*v.x + v.y*v.y + v.z*v.z + v.w*v.w;
  #pragma unroll
  for (int off = 1; off < 64; off <<= 1) ss += __shfl_xor(ss, off, 64);
  const float s = 1.0f / fmaxf(sqrtf(ss), 1e-6f);
  if (lane == 0) { invn[row] = s; den[row] = 0.0f; }
  const float sc = s * 3.79828286f;   // sqrt(10 * log2(e))
  unsigned int w = __builtin_amdgcn_cvt_pk_fp8_f32(v.x * sc, v.y * sc, 0u, false);
  w = __builtin_amdgcn_cvt_pk_fp8_f32(v.z * sc, v.w * sc, w, true);
  ((unsigned int*)(xn + (size_t)row * DIM))[lane] = w;
}

// ---------------------------------------------------------------------------
// ROW-MAJOR triangular decode: t -> (tI, tJ>=tI).
// Row i starts at S(i) = i*(193-i)/2 (96, 95, ... pairs per row).
// ---------------------------------------------------------------------------
__device__ __forceinline__ void decode_rowmajor(int t, int& tI, int& tJ) {
  int i = (int)((193.0f - sqrtf(193.0f * 193.0f - 8.0f * (float)t)) * 0.5f);
  if (i < 0) i = 0;
  while ((i + 1) * (193 - (i + 1)) / 2 <= t) i++;   // S(i+1) <= t -> advance
  while (i * (193 - i) / 2 > t) i--;                // S(i)  > t  -> back up
  tI = i;
  tJ = i + (t - i * (193 - i) / 2);
}

// Raw workgroup barrier: lgkmcnt-only (covers ds_write/ds_read completion),
// does NOT drain vmcnt — so prefetch global loads stay in flight across it.
#define BARRIER_LGKM() asm volatile("s_waitcnt lgkmcnt(0)\n\ts_barrier" ::: "memory")

// ---------------------------------------------------------------------------
// Kernel 2: PERSISTENT symmetric triangular GEMM, MX-scaled fp8 32x32x64,
// R12 shape (256 thr, 4 waves 2x2, 2 blocks/CU), A-panel reuse.
//
// R19 — R18 with the butterfly completed (R18 bug: masks {8,4,2,1} sum
// only the 16 lanes sharing bit4; bit4 was then used to SELECT mi, so
// each rowAcc held exactly HALF the true row sum -> absmax 0.875).
// Structure:
//   * forward tile only: acc = A·B^T.  E symmetric + mask transpose-
//     symmetric => mirror tile's den contribution = masked ROW sums of acc.
//   * MULTI-VALUE butterfly: 4 halving steps (masks 8,4,2,1) reduce the 16
//     row partials per mi to 1 register = half-sum over the lane's bit4
//     group of row (l31&15).  Then ONE mask-16 exchange completes BOTH mi
//     sums at once: each lane keeps the array its flush slot needs
//     (mi = l31>>4) and receives the partner half of that same array.
//   * CROSS-PAIR row accumulation: same tI panel for ~9 consecutive pairs
//     -> accumulate row sums in ONE register, flush with a single 64-lane
//     coalesced atomic on tI change / loop end.
//   * CROSS-BARRIER B PREFETCH: accT removal freed 64 VGPR -> issue next
//     pair's 8 dwordx4 B loads right after the K-loop barrier; L2 latency
//     hides under the exp2 epilogue; next iteration's ds_write carries the
//     vmcnt data dep.
//
// LDS: 32-B-unit XOR swizzle  addr = row*256 + ((k32 ^ (row&7))*32) + sub16
// C/D layout (HW-verified): col = lane&31, row = (reg&3)+8*(reg>>2)+4*half.
// Mask: exclude iff col%4 == row%4  ->  ((l31 ^ r) & 3) == 0.
// ---------------------------------------------------------------------------
__global__ __launch_bounds__(256, 2) void gemm_den_kernel(const uint8_t* __restrict__ xn,
                                                          float* __restrict__ den) {
  __shared__ __align__(16) uint8_t As[128 * 256];   // 32 KB (resident per row)
  __shared__ __align__(16) uint8_t Bs[128 * 256];   // 32 KB (per pair)

  const int tid  = threadIdx.x;
  const int wave = tid >> 6, lane = tid & 63;
  const int wr   = wave >> 1, wc = wave & 1;
  const int l31  = lane & 31, half = lane >> 5;
  const int e7   = l31 & 7;
  const int rowA0 = (wr * 64 + l31) * 256;
  const int rowB0 = (wc * 64 + l31) * 256;
  // per-lane row slot for the row-sum flush (butterfly output mapping):
  // mi = l31>>4, local row = (q&3)+8*(q>>2)+4*half with q = l31&15.
  const int rowOff = wr * 64 + ((l31 >> 4) << 5) + (l31 & 3) + (((l31 >> 2) & 3) << 3) + (half << 2);

  // per-thread staging maps (constant across pairs)
  size_t goff[8]; int wadr[8];
  #pragma unroll
  for (int c = 0; c < 8; c++) {
    const int q   = c * 256 + tid;
    const int row = q >> 4, k16 = q & 15;
    goff[c] = (size_t)row * DIM + (size_t)k16 * 16;
    wadr[c] = row * 256 + (((k16 >> 1) ^ (row & 7)) * 32) + (k16 & 1) * 16;
  }

  // contiguous chunk of row-major pairs
  const int b     = blockIdx.x;
  const int start = (int)((long)b * NPAIR / NBLOCKS);
  const int end   = (int)((long)(b + 1) * NPAIR / NBLOCKS);

  int tI, tJ;
  decode_rowmajor(start, tI, tJ);
  int prevI = -1;
  float rowAcc = 0.0f;
  int4 chB[8];
  bool havePre = false;

  for (int t = start; t < end; t++) {
    const bool offd = (tI != tJ);
    const bool newA = (tI != prevI);

    // flush accumulated row sums when the A panel changes
    if (newA && prevI >= 0) {
      atomicAdd(&den[prevI * 128 + rowOff], rowAcc);
      rowAcc = 0.0f;
    }
    prevI = tI;

    // ---- stage B (prefetched except first iter) + A (on row change).
    if (!havePre) {
      const uint8_t* Bb = xn + (size_t)tJ * 128 * DIM;
      #pragma unroll
      for (int c = 0; c < 8; c++) chB[c] = *(const int4*)(Bb + goff[c]);
    }
    if (newA) {
      const uint8_t* Ab = xn + (size_t)tI * 128 * DIM;
      int4 chA[8];
      #pragma unroll
      for (int c = 0; c < 8; c++) chA[c] = *(const int4*)(Ab + goff[c]);
      #pragma unroll
      for (int c = 0; c < 8; c++) *(int4*)(As + wadr[c]) = chA[c];
    }
    #pragma unroll
    for (int c = 0; c < 8; c++) *(int4*)(Bs + wadr[c]) = chB[c];   // waits vmcnt via dep
    BARRIER_LGKM();   // ds_writes visible to all waves

    // ---- K-loop: 4 steps of K=64; 4 frag loads + 4 forward MFMA only.
    f32x16 acc[2][2] = {};
    #pragma unroll
    for (int ks = 0; ks < 4; ks++) {
      const int u = ((2 * ks + half) ^ e7) * 32;
      i32x8 af[2], bf[2];
      af[0] = *(const i32x8*)(As + rowA0 + u);
      af[1] = *(const i32x8*)(As + rowA0 + 32 * 256 + u);
      bf[0] = *(const i32x8*)(Bs + rowB0 + u);
      bf[1] = *(const i32x8*)(Bs + rowB0 + 32 * 256 + u);
      #pragma unroll
      for (int mi = 0; mi < 2; mi++)
        #pragma unroll
        for (int ni = 0; ni < 2; ni++)
          acc[mi][ni] = __builtin_amdgcn_mfma_scale_f32_32x32x64_f8f6f4(
              af[mi], bf[ni], acc[mi][ni], 0, 0, 0, 0x7F7F7F7F, 0, 0x7F7F7F7F);
    }
    BARRIER_LGKM();   // all LDS reads done before next iteration's ds_writes

    const int curJ = tJ;

    // ---- prefetch next pair's B into registers (latency hides under epilogue)
    if (t + 1 < end) {
      decode_rowmajor(t + 1, tI, tJ);
      const uint8_t* Bb = xn + (size_t)tJ * 128 * DIM;
      #pragma unroll
      for (int c = 0; c < 8; c++) chB[c] = *(const int4*)(Bb + goff[c]);
      havePre = true;
    }

    // ---- epilogue: E = exp2(acc) once per element; masked col sums ->
    // den[curJ cols]; masked row sums (multi-value butterfly) -> rowAcc.
    {
      const int colBaseF = curJ * 128 + wc * 64;
      float cs0 = 0.0f, cs1 = 0.0f;
      float rs0[16], rs1[16];
      #pragma unroll
      for (int r = 0; r < 16; r++) {
        const bool inc = ((l31 ^ r) & 3) != 0;   // include iff col%4 != row%4
        const float a0 = inc ? __builtin_amdgcn_exp2f(acc[0][0][r]) : 0.0f;
        const float a1 = inc ? __builtin_amdgcn_exp2f(acc[0][1][r]) : 0.0f;
        const float b0 = inc ? __builtin_amdgcn_exp2f(acc[1][0][r]) : 0.0f;
        const float b1 = inc ? __builtin_amdgcn_exp2f(acc[1][1][r]) : 0.0f;
        cs0 += a0 + b0;
        cs1 += a1 + b1;
        rs0[r] = a0 + a1;      // row partials, mi = 0 (cols ni=0 and ni=1)
        rs1[r] = b0 + b1;      // row partials, mi = 1
      }
      if (offd) {
        // 4 halving steps: after these, lane l31 holds in rs*[0] the
        // HALF-sum (over its bit4 group of 16 lanes) of row (l31&15).
        #pragma unroll
        for (int m = 8; m >= 1; m >>= 1) {
          #pragma unroll
          for (int j = 0; j < m; j++) {
            {
              const float tsend = (l31 & m) ? rs0[j] : rs0[j + m];
              const float o = __shfl_xor(tsend, m, 64);
              rs0[j] = ((l31 & m) ? rs0[j + m] : rs0[j]) + o;
            }
            {
              const float tsend = (l31 & m) ? rs1[j] : rs1[j + m];
              const float o = __shfl_xor(tsend, m, 64);
              rs1[j] = ((l31 & m) ? rs1[j + m] : rs1[j]) + o;
            }
          }
        }
        // mask-16 combine (R19 FIX): each lane keeps the array its flush
        // slot (mi = l31>>4) needs and receives the partner bit4-group's
        // half of that SAME array -> full 32-lane row sums for both mi.
        {
          const float tsend = (l31 & 16) ? rs0[0] : rs1[0];   // what partner needs
          const float o     = __shfl_xor(tsend, 16, 64);
          const float keep  = (l31 & 16) ? rs1[0] : rs0[0];   // what we need
          rowAcc += keep + o;
        }
      }
      cs0 += __shfl_xor(cs0, 32, 64);
      cs1 += __shfl_xor(cs1, 32, 64);
      if (half == 0) {
        atomicAdd(&den[colBaseF + l31], cs0);
        atomicAdd(&den[colBaseF + 32 + l31], cs1);
      }
    }
  }
  // final flush of the last row panel
  if (prevI >= 0) atomicAdd(&den[prevI * 128 + rowOff], rowAcc);
}

// ---------------------------------------------------------------------------
// Kernel 3: numerators (fp32, exact path) + final loss.
// ---------------------------------------------------------------------------
__global__ __launch_bounds__(256) void loss_kernel(const float* __restrict__ x,
                                                   const float* __restrict__ invn,
                                                   const float* __restrict__ den,
                                                   float* __restrict__ out) {
  __shared__ float part[4];
  const int wave = threadIdx.x >> 6, lane = threadIdx.x & 63;
  const int p = blockIdx.x * 4 + wave;
  const float4 a = ((const float4*)(x + (size_t)p * DIM))[lane];
  const float4 b = ((const float4*)(x + (size_t)(BATCH_ + p) * DIM))[lane];
  const float4 c = ((const float4*)(x + (size_t)(2*BATCH_ + p) * DIM))[lane];
  float d12 = a.x*b.x + a.y*b.y + a.z*b.z + a.w*b.w;
  float d13 = a.x*c.x + a.y*c.y + a.z*c.z + a.w*c.w;
  float d23 = b.x*c.x + b.y*c.y + b.z*c.z + b.w*c.w;
  #pragma unroll
  for (int off = 1; off < 64; off <<= 1) {
    d12 += __shfl_xor(d12, off, 64);
    d13 += __shfl_xor(d13, off, 64);
    d23 += __shfl_xor(d23, off, 64);
  }
  if (lane == 0) {
    const float s1 = invn[p], s2 = invn[BATCH_ + p], s3 = invn[2*BATCH_ + p];
    const float z12 = d12 * s1 * s2 * 10.0f;
    const float z13 = d13 * s1 * s3 * 10.0f;
    const float z23 = d23 * s2 * s3 * 10.0f;
    const float n12 = __expf(z12), n13 = __expf(z13), n23 = __expf(z23);
    const float e1 = den[p], e2 = den[BATCH_ + p], e3 = den[2*BATCH_ + p];
    part[wave] = __logf(n12 + e1) + __logf(n12 + e2) - 2.0f * z12
               + __logf(n13 + e1) + __logf(n13 + e3) - 2.0f * z13
               + __logf(n23 + e2) + __logf(n23 + e3) - 2.0f * z23;
  }
  __syncthreads();
  if (threadIdx.x == 0) {
    atomicAdd(out, (part[0] + part[1] + part[2] + part[3]) * (1.0f / (2.0f * BATCH_)));
  }
}

// ---------------------------------------------------------------------------
extern "C" void kernel_launch(void* const* d_in, const int* in_sizes, int n_in,
                              void* d_out, int out_size, void* d_ws, size_t ws_size,
                              hipStream_t stream) {
  const float* x = (const float*)d_in[0];
  float* out = (float*)d_out;

  char* ws = (char*)d_ws;
  uint8_t* xn   = (uint8_t*)ws;                                      // 3 MB fp8
  float*   invn = (float*)(ws + (size_t)BS_TOT * DIM);               // 48 KB
  float*   den  = (float*)(ws + (size_t)BS_TOT * DIM + BS_TOT * 4);  // 48 KB

  normalize_kernel<<<BS_TOT / 4, 256, 0, stream>>>(x, xn, invn, den, out, out_size);
  gemm_den_kernel<<<NBLOCKS, 256, 0, stream>>>(xn, den);
  loss_kernel<<<BATCH_ / 4, 256, 0, stream>>>(x, invn, den, out);
}

// Round 4
// 123.109 us; speedup vs baseline: 1.8392x; 1.8392x over previous
//
#include <hip/hip_runtime.h>
#include <hip/hip_bf16.h>
#include <cstdint>
#include <cstddef>

// Problem constants
#define BS_TOT  12288   // 3 * 4096 rows
#define DIM     256     // embedding dim
#define BATCH_  4096
#define NTILE   96      // BS_TOT / 128
#define NPAIR   4656    // NTILE*(NTILE+1)/2 — triangular tile pairs (incl diag)
#define NBLOCKS 512     // persistent, 2 blocks/CU; ~9 contiguous pairs each

typedef float f32x16 __attribute__((ext_vector_type(16)));
typedef int   i32x8  __attribute__((ext_vector_type(8)));

// ---------------------------------------------------------------------------
// Kernel 1: row-normalize -> fp8 e4m3 rows scaled by sqrt(10*log2(e)):
// acc = 10*log2(e)*cos, so epilogue exp(10 cos) = exp2(acc) = bare v_exp_f32.
// Also fp32 inv-norms (exact numerator path) + zero den + zero out.
// ---------------------------------------------------------------------------
__global__ __launch_bounds__(256) void normalize_kernel(const float* __restrict__ x,
                                                        uint8_t* __restrict__ xn,
                                                        float* __restrict__ invn,
                                                        float* __restrict__ den,
                                                        float* __restrict__ out,
                                                        int osz) {
  if (blockIdx.x == 0 && (int)threadIdx.x < osz) out[threadIdx.x] = 0.0f;
  const int wave = threadIdx.x >> 6;
  const int lane = threadIdx.x & 63;
  const int row  = blockIdx.x * 4 + wave;
  const float4 v = ((const float4*)(x + (size_t)row * DIM))[lane];
  float ss = v.x*v.x + v.y*v.y + v.z*v.z + v.w*v.w;
  #pragma unroll
  for (int off = 1; off < 64; off <<= 1) ss += __shfl_xor(ss, off, 64);
  const float s = 1.0f / fmaxf(sqrtf(ss), 1e-6f);
  if (lane == 0) { invn[row] = s; den[row] = 0.0f; }
  const float sc = s * 3.79828286f;   // sqrt(10 * log2(e))
  unsigned int w = __builtin_amdgcn_cvt_pk_fp8_f32(v.x * sc, v.y * sc, 0u, false);
  w = __builtin_amdgcn_cvt_pk_fp8_f32(v.z * sc, v.w * sc, w, true);
  ((unsigned int*)(xn + (size_t)row * DIM))[lane] = w;
}

// ---------------------------------------------------------------------------
// ROW-MAJOR triangular decode: t -> (tI, tJ>=tI).
// Row i starts at S(i) = i*(193-i)/2 (96, 95, ... pairs per row).
// ---------------------------------------------------------------------------
__device__ __forceinline__ void decode_rowmajor(int t, int& tI, int& tJ) {
  int i = (int)((193.0f - sqrtf(193.0f * 193.0f - 8.0f * (float)t)) * 0.5f);
  if (i < 0) i = 0;
  while ((i + 1) * (193 - (i + 1)) / 2 <= t) i++;   // S(i+1) <= t -> advance
  while (i * (193 - i) / 2 > t) i--;                // S(i)  > t  -> back up
  tI = i;
  tJ = i + (t - i * (193 - i) / 2);
}

// Raw workgroup barrier: lgkmcnt-only (covers ds_write/ds_read completion),
// does NOT drain vmcnt — so epilogue atomics stay in flight across it.
#define BARRIER_LGKM() asm volatile("s_waitcnt lgkmcnt(0)\n\ts_barrier" ::: "memory")

// ---------------------------------------------------------------------------
// Kernel 2: PERSISTENT symmetric triangular GEMM, MX-scaled fp8 32x32x64,
// R12 shape (256 thr, 4 waves 2x2, 2 blocks/CU), A-panel reuse.
//
// R20 — transpose reuse within the 128-VGPR budget (R19 post-mortem: the
// correct butterfly + held B-prefetch spilled -> 250 MB scratch traffic,
// 159 us).  Changes vs R19:
//   * NO cross-barrier register prefetch (R14/R16/R19 all spilled; staging
//     registers are transient within an iteration, R12-proven).
//   * FUSED m=8 butterfly step: r and r+8 share the exclusion mask
//     ((r+8)&3 == r&3), so generate their exp2s together and combine
//     immediately -> row-partial arrays are 8+8 live registers, not 16+16.
//     Shuffle count unchanged (31 per off-diag pair).
//   * goff staging map as int (offsets < 3 MB), -8 VGPRs.
// Structure (verified in R19, absmax 0.0):
//   * forward tile only: acc = A·B^T.  E symmetric + mask transpose-
//     symmetric => mirror tile's den contribution = masked ROW sums of acc.
//   * butterfly output: lane l31 holds full 32-lane row sum of local row
//     q=(l31&15) for mi=(l31>>4); cross-pair accumulated in ONE register,
//     flushed with one coalesced 64-lane atomic per tI change.
//
// LDS: 32-B-unit XOR swizzle  addr = row*256 + ((k32 ^ (row&7))*32) + sub16
// C/D layout (HW-verified): col = lane&31, row = (reg&3)+8*(reg>>2)+4*half.
// Mask: exclude iff col%4 == row%4  ->  ((l31 ^ r) & 3) == 0.
// ---------------------------------------------------------------------------
__global__ __launch_bounds__(256, 2) void gemm_den_kernel(const uint8_t* __restrict__ xn,
                                                          float* __restrict__ den) {
  __shared__ __align__(16) uint8_t As[128 * 256];   // 32 KB (resident per row)
  __shared__ __align__(16) uint8_t Bs[128 * 256];   // 32 KB (per pair)

  const int tid  = threadIdx.x;
  const int wave = tid >> 6, lane = tid & 63;
  const int wr   = wave >> 1, wc = wave & 1;
  const int l31  = lane & 31, half = lane >> 5;
  const int e7   = l31 & 7;
  const int rowA0 = (wr * 64 + l31) * 256;
  const int rowB0 = (wc * 64 + l31) * 256;
  // per-lane row slot for the row-sum flush (butterfly output mapping):
  // mi = l31>>4, local row = (q&3)+8*(q>>2)+4*half with q = l31&15.
  const int rowOff = wr * 64 + ((l31 >> 4) << 5) + (l31 & 3) + (((l31 >> 2) & 3) << 3) + (half << 2);

  // per-thread staging maps (constant across pairs); int offsets (< 3 MB)
  int goff[8]; int wadr[8];
  #pragma unroll
  for (int c = 0; c < 8; c++) {
    const int q   = c * 256 + tid;
    const int row = q >> 4, k16 = q & 15;
    goff[c] = row * DIM + k16 * 16;
    wadr[c] = row * 256 + (((k16 >> 1) ^ (row & 7)) * 32) + (k16 & 1) * 16;
  }

  // contiguous chunk of row-major pairs
  const int b     = blockIdx.x;
  const int start = (int)((long)b * NPAIR / NBLOCKS);
  const int end   = (int)((long)(b + 1) * NPAIR / NBLOCKS);

  int prevI = -1;
  float rowAcc = 0.0f;

  for (int t = start; t < end; t++) {
    int tI, tJ;
    decode_rowmajor(t, tI, tJ);
    const bool offd = (tI != tJ);
    const bool newA = (tI != prevI);

    // flush accumulated row sums when the A panel changes
    if (newA && prevI >= 0) {
      atomicAdd(&den[prevI * 128 + rowOff], rowAcc);
      rowAcc = 0.0f;
    }
    prevI = tI;

    // ---- stage B (always) + A (on row change); registers are transient.
    {
      const uint8_t* Bb = xn + (size_t)tJ * 128 * DIM;
      int4 chB[8];
      #pragma unroll
      for (int c = 0; c < 8; c++) chB[c] = *(const int4*)(Bb + goff[c]);
      if (newA) {
        const uint8_t* Ab = xn + (size_t)tI * 128 * DIM;
        int4 chA[8];
        #pragma unroll
        for (int c = 0; c < 8; c++) chA[c] = *(const int4*)(Ab + goff[c]);
        #pragma unroll
        for (int c = 0; c < 8; c++) *(int4*)(As + wadr[c]) = chA[c];
      }
      #pragma unroll
      for (int c = 0; c < 8; c++) *(int4*)(Bs + wadr[c]) = chB[c];
    }
    BARRIER_LGKM();   // ds_writes visible to all waves

    // ---- K-loop: 4 steps of K=64; 4 frag loads + 4 forward MFMA only.
    f32x16 acc[2][2] = {};
    #pragma unroll
    for (int ks = 0; ks < 4; ks++) {
      const int u = ((2 * ks + half) ^ e7) * 32;
      i32x8 af[2], bf[2];
      af[0] = *(const i32x8*)(As + rowA0 + u);
      af[1] = *(const i32x8*)(As + rowA0 + 32 * 256 + u);
      bf[0] = *(const i32x8*)(Bs + rowB0 + u);
      bf[1] = *(const i32x8*)(Bs + rowB0 + 32 * 256 + u);
      #pragma unroll
      for (int mi = 0; mi < 2; mi++)
        #pragma unroll
        for (int ni = 0; ni < 2; ni++)
          acc[mi][ni] = __builtin_amdgcn_mfma_scale_f32_32x32x64_f8f6f4(
              af[mi], bf[ni], acc[mi][ni], 0, 0, 0, 0x7F7F7F7F, 0, 0x7F7F7F7F);
    }
    BARRIER_LGKM();   // all LDS reads done before next iteration's ds_writes

    // ---- epilogue: E = exp2(acc) once per element; masked col sums ->
    // den[tJ cols]; masked row sums (fused multi-value butterfly) -> rowAcc.
    {
      const int colBaseF = tJ * 128 + wc * 64;
      float cs0 = 0.0f, cs1 = 0.0f;
      float rs0[8], rs1[8];
      #pragma unroll
      for (int r = 0; r < 8; r++) {
        const bool inc = ((l31 ^ r) & 3) != 0;   // same mask for r and r+8
        const float a0  = inc ? __builtin_amdgcn_exp2f(acc[0][0][r])     : 0.0f;
        const float a1  = inc ? __builtin_amdgcn_exp2f(acc[0][1][r])     : 0.0f;
        const float b0  = inc ? __builtin_amdgcn_exp2f(acc[1][0][r])     : 0.0f;
        const float b1  = inc ? __builtin_amdgcn_exp2f(acc[1][1][r])     : 0.0f;
        const float a0h = inc ? __builtin_amdgcn_exp2f(acc[0][0][r + 8]) : 0.0f;
        const float a1h = inc ? __builtin_amdgcn_exp2f(acc[0][1][r + 8]) : 0.0f;
        const float b0h = inc ? __builtin_amdgcn_exp2f(acc[1][0][r + 8]) : 0.0f;
        const float b1h = inc ? __builtin_amdgcn_exp2f(acc[1][1][r + 8]) : 0.0f;
        cs0 += a0 + b0 + a0h + b0h;
        cs1 += a1 + b1 + a1h + b1h;
        // fused m=8 butterfly step: combine row partials r (lo) and r+8 (hi)
        const float lo0 = a0 + a1, hi0 = a0h + a1h;   // mi = 0
        const float lo1 = b0 + b1, hi1 = b0h + b1h;   // mi = 1
        {
          const float tsend = (l31 & 8) ? lo0 : hi0;
          const float o = __shfl_xor(tsend, 8, 64);
          rs0[r] = ((l31 & 8) ? hi0 : lo0) + o;
        }
        {
          const float tsend = (l31 & 8) ? lo1 : hi1;
          const float o = __shfl_xor(tsend, 8, 64);
          rs1[r] = ((l31 & 8) ? hi1 : lo1) + o;
        }
      }
      if (offd) {
        // remaining halving steps (masks 4,2,1) on the 8-element arrays
        #pragma unroll
        for (int m = 4; m >= 1; m >>= 1) {
          #pragma unroll
          for (int j = 0; j < m; j++) {
            {
              const float tsend = (l31 & m) ? rs0[j] : rs0[j + m];
              const float o = __shfl_xor(tsend, m, 64);
              rs0[j] = ((l31 & m) ? rs0[j + m] : rs0[j]) + o;
            }
            {
              const float tsend = (l31 & m) ? rs1[j] : rs1[j + m];
              const float o = __shfl_xor(tsend, m, 64);
              rs1[j] = ((l31 & m) ? rs1[j + m] : rs1[j]) + o;
            }
          }
        }
        // mask-16 combine: each lane keeps the array its flush slot needs
        // (mi = l31>>4) and receives the partner bit4-group's half of that
        // SAME array -> full 32-lane row sums for both mi at once.
        {
          const float tsend = (l31 & 16) ? rs0[0] : rs1[0];   // what partner needs
          const float o     = __shfl_xor(tsend, 16, 64);
          const float keep  = (l31 & 16) ? rs1[0] : rs0[0];   // what we need
          rowAcc += keep + o;
        }
      }
      cs0 += __shfl_xor(cs0, 32, 64);
      cs1 += __shfl_xor(cs1, 32, 64);
      if (half == 0) {
        atomicAdd(&den[colBaseF + l31], cs0);
        atomicAdd(&den[colBaseF + 32 + l31], cs1);
      }
    }
  }
  // final flush of the last row panel
  if (prevI >= 0) atomicAdd(&den[prevI * 128 + rowOff], rowAcc);
}

// ---------------------------------------------------------------------------
// Kernel 3: numerators (fp32, exact path) + final loss.
// ---------------------------------------------------------------------------
__global__ __launch_bounds__(256) void loss_kernel(const float* __restrict__ x,
                                                   const float* __restrict__ invn,
                                                   const float* __restrict__ den,
                                                   float* __restrict__ out) {
  __shared__ float part[4];
  const int wave = threadIdx.x >> 6, lane = threadIdx.x & 63;
  const int p = blockIdx.x * 4 + wave;
  const float4 a = ((const float4*)(x + (size_t)p * DIM))[lane];
  const float4 b = ((const float4*)(x + (size_t)(BATCH_ + p) * DIM))[lane];
  const float4 c = ((const float4*)(x + (size_t)(2*BATCH_ + p) * DIM))[lane];
  float d12 = a.x*b.x + a.y*b.y + a.z*b.z + a.w*b.w;
  float d13 = a.x*c.x + a.y*c.y + a.z*c.z + a.w*c.w;
  float d23 = b.x*c.x + b.y*c.y + b.z*c.z + b.w*c.w;
  #pragma unroll
  for (int off = 1; off < 64; off <<= 1) {
    d12 += __shfl_xor(d12, off, 64);
    d13 += __shfl_xor(d13, off, 64);
    d23 += __shfl_xor(d23, off, 64);
  }
  if (lane == 0) {
    const float s1 = invn[p], s2 = invn[BATCH_ + p], s3 = invn[2*BATCH_ + p];
    const float z12 = d12 * s1 * s2 * 10.0f;
    const float z13 = d13 * s1 * s3 * 10.0f;
    const float z23 = d23 * s2 * s3 * 10.0f;
    const float n12 = __expf(z12), n13 = __expf(z13), n23 = __expf(z23);
    const float e1 = den[p], e2 = den[BATCH_ + p], e3 = den[2*BATCH_ + p];
    part[wave] = __logf(n12 + e1) + __logf(n12 + e2) - 2.0f * z12
               + __logf(n13 + e1) + __logf(n13 + e3) - 2.0f * z13
               + __logf(n23 + e2) + __logf(n23 + e3) - 2.0f * z23;
  }
  __syncthreads();
  if (threadIdx.x == 0) {
    atomicAdd(out, (part[0] + part[1] + part[2] + part[3]) * (1.0f / (2.0f * BATCH_)));
  }
}

// ---------------------------------------------------------------------------
extern "C" void kernel_launch(void* const* d_in, const int* in_sizes, int n_in,
                              void* d_out, int out_size, void* d_ws, size_t ws_size,
                              hipStream_t stream) {
  const float* x = (const float*)d_in[0];
  float* out = (float*)d_out;

  char* ws = (char*)d_ws;
  uint8_t* xn   = (uint8_t*)ws;                                      // 3 MB fp8
  float*   invn = (float*)(ws + (size_t)BS_TOT * DIM);               // 48 KB
  float*   den  = (float*)(ws + (size_t)BS_TOT * DIM + BS_TOT * 4);  // 48 KB

  normalize_kernel<<<BS_TOT / 4, 256, 0, stream>>>(x, xn, invn, den, out, out_size);
  gemm_den_kernel<<<NBLOCKS, 256, 0, stream>>>(xn, den);
  loss_kernel<<<BATCH_ / 4, 256, 0, stream>>>(x, invn, den, out);
}